// Round 2
// baseline (5055.635 us; speedup 1.0000x reference)
//
#include <hip/hip_runtime.h>
#include <cstdint>
#include <cmath>

#define T_STEPS 1460
#define N_GRID  2000
#define UH_LEN  15
#define NZ      1e-6f
static const size_t TG = (size_t)T_STEPS * N_GRID;

// sigmoid-bounded parameter transform (matches ref: lo + sigmoid(x)*(hi-lo))
__device__ __forceinline__ float pb(float x, float lo, float hi) {
    float s = 1.0f / (1.0f + expf(-x));
    return lo + s * (hi - lo);
}

__device__ __forceinline__ float clip01(float x) {
    return fminf(fmaxf(x, NZ), 1.0f);
}

// gate = round(sigmoid(x)) with round-half-to-even.
// For |x| > 1e-4 this is exactly (x > 0).  Near 0, use double + rint.
__device__ __forceinline__ float gatef(float x) {
    if (fabsf(x) < 1e-4f) {
        double s = 1.0 / (1.0 + exp(-(double)x));
        return (float)rint(s);
    }
    return (x > 0.0f) ? 1.0f : 0.0f;
}

// ---------------------------------------------------------------------------
// Kernel 1: per-cell unit hydrograph weights (softmax over 15 lags, 2 sets)
// ---------------------------------------------------------------------------
__global__ __launch_bounds__(256)
void uh_kernel(const float* __restrict__ hyb,
               float* __restrict__ uh1, float* __restrict__ uh2)
{
    const int g = blockIdx.x * 256 + threadIdx.x;
    if (g >= N_GRID) return;
    const float* h = hyb + (size_t)g * 32;
    const float a1 = pb(h[28], 0.3f, 20.0f);
    const float b1 = pb(h[29], 0.01f, 5.0f);
    const float a2 = pb(h[30], 0.5f, 13.0f);
    const float b2 = pb(h[31], 0.15f, 1.5f);

    float lw[UH_LEN];
    {
        float m = -1e30f;
        #pragma unroll
        for (int k = 0; k < UH_LEN; ++k) {
            const float kk = (float)(k + 1);
            lw[k] = (a1 - 1.0f) * logf(kk) - kk / b1;
            m = fmaxf(m, lw[k]);
        }
        float s = 0.0f;
        #pragma unroll
        for (int k = 0; k < UH_LEN; ++k) { lw[k] = expf(lw[k] - m); s += lw[k]; }
        const float inv = 1.0f / s;
        #pragma unroll
        for (int k = 0; k < UH_LEN; ++k) uh1[k * N_GRID + g] = lw[k] * inv;
    }
    {
        float m = -1e30f;
        #pragma unroll
        for (int k = 0; k < UH_LEN; ++k) {
            const float kk = (float)(k + 1);
            lw[k] = (a2 - 1.0f) * logf(kk) - kk / b2;
            m = fmaxf(m, lw[k]);
        }
        float s = 0.0f;
        #pragma unroll
        for (int k = 0; k < UH_LEN; ++k) { lw[k] = expf(lw[k] - m); s += lw[k]; }
        const float inv = 1.0f / s;
        #pragma unroll
        for (int k = 0; k < UH_LEN; ++k) uh2[k * N_GRID + g] = lw[k] * inv;
    }
}

// ---------------------------------------------------------------------------
// Kernel P: parallel pre-pass.  Transposes (T,G,24)+(T,G,3) into plane-major
// (21,T,G) fp32 planes and hoists all state-independent math out of the scan:
//   plane 0: temp   1: pet   2: pshed (rain-or-snow after canopy gates)
//   3..8:  normalized infiltration weights
//   9..14: normalized bf1 weights
//   15..20: normalized bf2 weights
// gate byte: bit0=g4 bit1=g5 bit2=g0 bit3=g1
// ---------------------------------------------------------------------------
__global__ __launch_bounds__(256)
void prep_kernel(const float* __restrict__ xphy,
                 const float* __restrict__ wts,
                 const float* __restrict__ hyb,
                 float* __restrict__ planes,
                 unsigned char* __restrict__ gate_o)
{
    const int g = blockIdx.x * 256 + threadIdx.x;
    if (g >= N_GRID) return;
    const int t = blockIdx.y;
    const size_t idx = (size_t)t * N_GRID + g;

    const float* xp = xphy + idx * 3;
    const float prcp = xp[0], temp = xp[1], pet = xp[2];

    float w[24];
    const float4* wp = (const float4*)(wts + idx * 24);
    #pragma unroll
    for (int k = 0; k < 6; ++k) {
        float4 v = wp[k];
        w[4*k] = v.x; w[4*k+1] = v.y; w[4*k+2] = v.z; w[4*k+3] = v.w;
    }

    // three 6-way softmaxes (no max-sub needed: |w| small, N(0,1))
    float e[18];
    #pragma unroll
    for (int k = 0; k < 18; ++k) e[k] = __expf(w[k]);
    float s0 = 0.f, s1 = 0.f, s2 = 0.f;
    #pragma unroll
    for (int k = 0; k < 6; ++k) { s0 += e[k]; s1 += e[6+k]; s2 += e[12+k]; }
    const float r0 = 1.0f / s0, r1 = 1.0f / s1, r2 = 1.0f / s2;

    const float g0 = gatef(w[18]);
    const float g1 = gatef(w[19]);
    const float g2 = gatef(w[20]);
    const float g3 = gatef(w[21]);
    const float g4 = gatef(w[22]);
    const float g5 = gatef(w[23]);

    const float* h = hyb + (size_t)g * 32;
    const float fc = pb(h[24], 0.0f, 1.0f);
    const float fs = pb(h[25], 0.0f, 1.0f);
    const float canopy = pet * (fc * (1.0f - fs));
    // rain and snowf are mutually exclusive; fold canopy interception here
    const float pshed = (temp >= 0.0f) ? fmaxf(prcp - canopy * g2, 0.0f)
                                       : fmaxf(prcp - canopy * g3, 0.0f);

    planes[0 * TG + idx] = temp;
    planes[1 * TG + idx] = pet;
    planes[2 * TG + idx] = pshed;
    #pragma unroll
    for (int k = 0; k < 6; ++k) {
        planes[(3 + k)  * TG + idx] = e[k]      * r0;
        planes[(9 + k)  * TG + idx] = e[6 + k]  * r1;
        planes[(15 + k) * TG + idx] = e[12 + k] * r2;
    }
    gate_o[idx] = (unsigned char)((g4 > 0.5f ? 1 : 0) | (g5 > 0.5f ? 2 : 0) |
                                  (g0 > 0.5f ? 4 : 0) | (g1 > 0.5f ? 8 : 0));
}

// ---------------------------------------------------------------------------
// Kernel S-A: the sequential scan reading coalesced planes.  One thread per
// cell; 2x-unrolled main loop with two register buffers = depth-2 prefetch.
// ---------------------------------------------------------------------------
struct StepIn {
    float temp, pet, pshed;
    float wi[6], wb1[6], wb2[6];
    float g0, g1;
};

__device__ __forceinline__ void load_step(const float* __restrict__ planes,
                                          const unsigned char* __restrict__ gates,
                                          size_t idx, StepIn& s)
{
    s.temp  = planes[0 * TG + idx];
    s.pet   = planes[1 * TG + idx];
    s.pshed = planes[2 * TG + idx];
    #pragma unroll
    for (int k = 0; k < 6; ++k) s.wi[k]  = planes[(3 + k)  * TG + idx];
    #pragma unroll
    for (int k = 0; k < 6; ++k) s.wb1[k] = planes[(9 + k)  * TG + idx];
    #pragma unroll
    for (int k = 0; k < 6; ++k) s.wb2[k] = planes[(15 + k) * TG + idx];
    const unsigned char b = gates[idx];
    s.g0 = (b & 4) ? 1.0f : 0.0f;
    s.g1 = (b & 8) ? 1.0f : 0.0f;
}

struct Params {
    float inf_pc, hbv_beta, vic_bexp, hmets_al;
    float msw1, inv_msw1, msw2, inv_msw2;
    float perc_fac, sfc, crise;
    float Tbf, Kf, ddf_min, ddf_plus, Kcum, Tbm, swi;
    float inv_x3_1, pow10_1, bfn1, bfmax1, lam, b1o4, b1o5, th1;
    float inv_x3_2, pow10_2, bfn2, bfmax2;
};

struct State { float snow, liq, cum, sw1, sw2; };

__device__ __forceinline__ void do_step(State& st, const StepIn& in, const Params& P,
                                        float& surf_out, float& base_out)
{
    const float temp = in.temp, pet = in.pet;
    const float rain  = (temp >= 0.0f) ? in.pshed : 0.0f;
    const float snowf = (temp <  0.0f) ? in.pshed : 0.0f;

    const float refreeze = fminf(st.liq, P.Kf * fmaxf(P.Tbf - temp, 0.0f));
    st.snow = st.snow + snowf + refreeze;
    st.liq  = st.liq - refreeze;
    const float ddf = P.ddf_min + P.ddf_plus * (1.0f - __expf(-P.Kcum * st.cum));
    const float melt = fminf(st.snow, ddf * fmaxf(temp - P.Tbm, 0.0f));
    st.snow -= melt;
    st.cum = (st.snow < NZ) ? NZ : (st.cum + melt);
    st.liq += melt;
    const float overflow = fmaxf(st.liq - P.swi * st.snow, 0.0f);
    st.liq -= overflow;
    const float wavail = rain + overflow;

    float sat1 = clip01(st.sw1 * P.inv_msw1);
    const float dry1 = clip01(1.0f - sat1);
    const float p1 = __powf(sat1, P.hbv_beta);
    const float p2 = __powf(dry1, P.vic_bexp);
    const float infil = wavail *
        (in.wi[0] * P.inf_pc + in.wi[1] * (1.0f - p1) + in.wi[2] * p2 +
         in.wi[3] * (P.hmets_al * dry1) + in.wi[4] * (1.0f - sat1 * sat1) + in.wi[5]);

    st.sw1 += infil;
    const float excess = fmaxf(st.sw1 - P.msw1, 0.0f);
    st.sw1 -= excess;
    surf_out = wavail - infil + excess;

    sat1 = clip01(st.sw1 * P.inv_msw1);
    const float perc = fminf(in.g0 * P.perc_fac * fmaxf(sat1 - P.sfc, 0.0f), st.sw1);
    st.sw1 -= perc; st.sw2 += perc;

    float sat2 = clip01(st.sw2 * P.inv_msw2);
    sat1 = clip01(st.sw1 * P.inv_msw1);
    const float capi = fminf(in.g1 * P.crise * (1.0f - sat1) * sat2, st.sw2);
    st.sw2 -= capi; st.sw1 += capi;

    sat1 = clip01(st.sw1 * P.inv_msw1);
    const float et = fminf(pet * sat1, st.sw1);
    st.sw1 -= et;

    sat1 = clip01(st.sw1 * P.inv_msw1);
    const float q = st.sw1 * P.inv_x3_1;
    const float q4 = (q * q) * (q * q);
    const float gr1 = st.sw1 * (1.0f - __powf(1.0f + q4, -0.25f));
    const float pw1 = __powf(sat1, P.bfn1);
    const float ex1 = __expf(P.lam * sat1) - 1.0f;
    const float bsum1 = in.wb1[0] * gr1 + in.wb1[1] * (P.pow10_1 * st.sw1) +
                        in.wb1[2] * (P.bfmax1 * pw1) + in.wb1[3] * (P.bfmax1 * sat1) +
                        in.wb1[4] * (P.b1o4 * ex1) +
                        in.wb1[5] * (P.b1o5 * fmaxf(sat1 - P.th1, 0.0f));
    const float bf1 = fminf(bsum1, st.sw1);
    st.sw1 -= bf1;

    sat2 = clip01(st.sw2 * P.inv_msw2);
    const float u = st.sw2 * P.inv_x3_2;
    const float u4 = (u * u) * (u * u);
    const float gr2 = st.sw2 * (1.0f - __powf(1.0f + u4, -0.25f));
    const float pw2 = __powf(sat2, P.bfn2);
    const float t10 = P.pow10_2 * st.sw2;
    const float bsum2 = in.wb2[0] * gr2 + in.wb2[1] * t10 +
                        in.wb2[2] * (P.bfmax2 * pw2) + in.wb2[3] * (P.bfmax2 * sat2) +
                        in.wb2[4] * (P.bfmax2 * sat2 * sat2) + in.wb2[5] * (t10 * sat2);
    const float bf2 = fminf(bsum2, st.sw2);
    st.sw2 -= bf2;

    base_out = bf1 + bf2;
}

__global__ __launch_bounds__(64)
void scan_planes_kernel(const float* __restrict__ planes,
                        const unsigned char* __restrict__ gates,
                        const float* __restrict__ hyb,
                        float* __restrict__ surf_o,
                        float* __restrict__ base_o)
{
    const int g = blockIdx.x * 64 + threadIdx.x;
    if (g >= N_GRID) return;

    const float* h = hyb + (size_t)g * 32;
    Params P;
    P.inf_pc   = pb(h[0],  0.0f,   1.0f);
    P.hbv_beta = pb(h[1],  0.5f,   3.0f);
    P.vic_bexp = pb(h[2],  0.001f, 3.0f);
    P.hmets_al = pb(h[3],  0.3f,   1.0f);
    const float x3_1 = pb(h[4],  20.0f,  300.0f);
    const float bfc1 = pb(h[5],  -8.0f,  -2.0f);
    P.bfn1     = pb(h[6],  1.0f,   5.0f);
    P.bfmax1   = pb(h[7],  0.1f,   200.0f);
    P.lam      = pb(h[8],  0.1f,   0.5f);
    P.th1      = pb(h[9],  0.0001f,0.9999f);
    const float max_perc = pb(h[10], 1.0f, 50.0f);
    P.sfc      = pb(h[11], 0.0001f,0.9999f);
    P.crise    = pb(h[12], 0.1f,   50.0f);
    P.bfmax2   = pb(h[13], 0.1f,   100.0f);
    const float x3_2 = pb(h[14], 50.0f,  500.0f);
    const float bfc2 = pb(h[15], -8.0f,  -2.0f);
    P.bfn2     = pb(h[16], 1.0f,   5.0f);
    P.Tbf      = pb(h[17], -5.0f,  2.0f);
    P.Kf       = pb(h[18], 0.0f,   5.0f);
    P.ddf_min  = pb(h[19], 1.5f,   3.0f);
    P.ddf_plus = pb(h[20], 0.0f,   5.0f);
    P.Kcum     = pb(h[21], 0.01f,  0.2f);
    P.Tbm      = pb(h[22], -1.0f,  1.0f);
    P.swi      = pb(h[23], 0.0f,   0.4f);
    P.msw1     = pb(h[26], 50.0f,  500.0f);
    P.msw2     = pb(h[27], 50.0f,  500.0f);
    P.inv_msw1 = 1.0f / P.msw1;
    P.inv_msw2 = 1.0f / P.msw2;
    P.pow10_1  = powf(10.0f, bfc1);
    P.pow10_2  = powf(10.0f, bfc2);
    P.inv_x3_1 = 1.0f / x3_1;
    P.inv_x3_2 = 1.0f / x3_2;
    P.b1o4     = P.bfmax1 / expm1f(P.lam);
    P.b1o5     = P.bfmax1 / (1.0f - P.th1);
    P.perc_fac = max_perc / (1.0f - P.sfc);

    State st; st.snow = NZ; st.liq = NZ; st.cum = NZ; st.sw1 = NZ; st.sw2 = NZ;

    StepIn A, B;
    load_step(planes, gates, (size_t)0 * N_GRID + g, A);
    load_step(planes, gates, (size_t)1 * N_GRID + g, B);

    for (int t = 0; t < T_STEPS; t += 2) {
        float surf, base;
        size_t o = (size_t)t * N_GRID + g;

        do_step(st, A, P, surf, base);
        surf_o[o] = surf; base_o[o] = base;
        {   // prefetch t+2 into A (clamped dummy reload near the end)
            const int tn = (t + 2 < T_STEPS) ? (t + 2) : t;
            load_step(planes, gates, (size_t)tn * N_GRID + g, A);
        }

        do_step(st, B, P, surf, base);
        surf_o[o + N_GRID] = surf; base_o[o + N_GRID] = base;
        {   // prefetch t+3 into B
            const int tn = (t + 3 < T_STEPS) ? (t + 3) : (t + 1);
            load_step(planes, gates, (size_t)tn * N_GRID + g, B);
        }
    }
}

// ---------------------------------------------------------------------------
// Kernel S-B (fallback when ws is small): round-1 scan, reads raw inputs.
// ---------------------------------------------------------------------------
__global__ __launch_bounds__(64)
void scan_kernel(const float* __restrict__ xphy,
                 const float* __restrict__ wts,
                 const float* __restrict__ hyb,
                 float* __restrict__ surf_o,
                 float* __restrict__ base_o,
                 unsigned char* __restrict__ gate_o)
{
    const int g = blockIdx.x * 64 + threadIdx.x;
    if (g >= N_GRID) return;

    const float* h = hyb + (size_t)g * 32;
    const float inf_pc   = pb(h[0],  0.0f,   1.0f);
    const float hbv_beta = pb(h[1],  0.5f,   3.0f);
    const float vic_bexp = pb(h[2],  0.001f, 3.0f);
    const float hmets_al = pb(h[3],  0.3f,   1.0f);
    const float x3_1     = pb(h[4],  20.0f,  300.0f);
    const float bfc1     = pb(h[5],  -8.0f,  -2.0f);
    const float bfn1     = pb(h[6],  1.0f,   5.0f);
    const float bfmax1   = pb(h[7],  0.1f,   200.0f);
    const float lam      = pb(h[8],  0.1f,   0.5f);
    const float th1      = pb(h[9],  0.0001f,0.9999f);
    const float max_perc = pb(h[10], 1.0f,   50.0f);
    const float sfc      = pb(h[11], 0.0001f,0.9999f);
    const float crise    = pb(h[12], 0.1f,   50.0f);
    const float bfmax2   = pb(h[13], 0.1f,   100.0f);
    const float x3_2     = pb(h[14], 50.0f,  500.0f);
    const float bfc2     = pb(h[15], -8.0f,  -2.0f);
    const float bfn2     = pb(h[16], 1.0f,   5.0f);
    const float Tbf      = pb(h[17], -5.0f,  2.0f);
    const float Kf       = pb(h[18], 0.0f,   5.0f);
    const float ddf_min  = pb(h[19], 1.5f,   3.0f);
    const float ddf_plus = pb(h[20], 0.0f,   5.0f);
    const float Kcum     = pb(h[21], 0.01f,  0.2f);
    const float Tbm      = pb(h[22], -1.0f,  1.0f);
    const float swi      = pb(h[23], 0.0f,   0.4f);
    const float fc       = pb(h[24], 0.0f,   1.0f);
    const float fs       = pb(h[25], 0.0f,   1.0f);
    const float msw1     = pb(h[26], 50.0f,  500.0f);
    const float msw2     = pb(h[27], 50.0f,  500.0f);

    const float inv_msw1  = 1.0f / msw1;
    const float inv_msw2  = 1.0f / msw2;
    const float canopy_fac = fc * (1.0f - fs);
    const float pow10_1   = powf(10.0f, bfc1);
    const float pow10_2   = powf(10.0f, bfc2);
    const float inv_x3_1  = 1.0f / x3_1;
    const float inv_x3_2  = 1.0f / x3_2;
    const float b1o4      = bfmax1 / expm1f(lam);
    const float b1o5      = bfmax1 / (1.0f - th1);
    const float perc_fac  = max_perc / (1.0f - sfc);

    float snow = NZ, liq = NZ, cum = NZ, sw1 = NZ, sw2 = NZ;

    float4 wc0, wc1, wc2, wc3, wc4, wc5;
    float xc0, xc1, xc2;
    {
        const float* xp = xphy + (size_t)g * 3;
        xc0 = xp[0]; xc1 = xp[1]; xc2 = xp[2];
        const float4* wp = (const float4*)(wts + (size_t)g * 24);
        wc0 = wp[0]; wc1 = wp[1]; wc2 = wp[2]; wc3 = wp[3]; wc4 = wp[4]; wc5 = wp[5];
    }

    for (int t = 0; t < T_STEPS; ++t) {
        const int tn = (t + 1 < T_STEPS) ? (t + 1) : t;
        float4 wn0, wn1, wn2, wn3, wn4, wn5;
        float xn0, xn1, xn2;
        {
            const float* xp = xphy + ((size_t)tn * N_GRID + g) * 3;
            xn0 = xp[0]; xn1 = xp[1]; xn2 = xp[2];
            const float4* wp = (const float4*)(wts + ((size_t)tn * N_GRID + g) * 24);
            wn0 = wp[0]; wn1 = wp[1]; wn2 = wp[2]; wn3 = wp[3]; wn4 = wp[4]; wn5 = wp[5];
        }

        const float prcp = xc0, temp = xc1, pet = xc2;
        const float g0 = gatef(wc4.z);
        const float g1 = gatef(wc4.w);
        const float g2 = gatef(wc5.x);
        const float g3 = gatef(wc5.y);
        const float g4 = gatef(wc5.z);
        const float g5 = gatef(wc5.w);

        float rain  = (temp >= 0.0f) ? prcp : 0.0f;
        float snowf = (temp <  0.0f) ? prcp : 0.0f;
        const float canopy = pet * canopy_fac;
        rain  = fmaxf(rain  - canopy * g2, 0.0f);
        snowf = fmaxf(snowf - canopy * g3, 0.0f);

        const float refreeze = fminf(liq, Kf * fmaxf(Tbf - temp, 0.0f));
        snow = snow + snowf + refreeze;
        liq  = liq - refreeze;
        const float ddf = ddf_min + ddf_plus * (1.0f - __expf(-Kcum * cum));
        const float melt = fminf(snow, ddf * fmaxf(temp - Tbm, 0.0f));
        snow -= melt;
        cum = (snow < NZ) ? NZ : (cum + melt);
        liq += melt;
        const float overflow = fmaxf(liq - swi * snow, 0.0f);
        liq -= overflow;
        const float wavail = rain + overflow;

        float sat1 = clip01(sw1 * inv_msw1);
        const float dry1 = clip01(1.0f - sat1);
        const float e0 = __expf(wc0.x), e1 = __expf(wc0.y), e2 = __expf(wc0.z),
                    e3 = __expf(wc0.w), e4 = __expf(wc1.x), e5 = __expf(wc1.y);
        const float rsi = 1.0f / (e0 + e1 + e2 + e3 + e4 + e5);
        const float p1 = __powf(sat1, hbv_beta);
        const float p2 = __powf(dry1, vic_bexp);
        const float infil = wavail * rsi *
            (e0 * inf_pc + e1 * (1.0f - p1) + e2 * p2 +
             e3 * (hmets_al * dry1) + e4 * (1.0f - sat1 * sat1) + e5);

        sw1 += infil;
        const float excess = fmaxf(sw1 - msw1, 0.0f);
        sw1 -= excess;
        const float surf = wavail - infil + excess;

        sat1 = clip01(sw1 * inv_msw1);
        const float perc = fminf(g0 * perc_fac * fmaxf(sat1 - sfc, 0.0f), sw1);
        sw1 -= perc; sw2 += perc;

        float sat2 = clip01(sw2 * inv_msw2);
        sat1 = clip01(sw1 * inv_msw1);
        const float capi = fminf(g1 * crise * (1.0f - sat1) * sat2, sw2);
        sw2 -= capi; sw1 += capi;

        sat1 = clip01(sw1 * inv_msw1);
        const float et = fminf(pet * sat1, sw1);
        sw1 -= et;

        sat1 = clip01(sw1 * inv_msw1);
        const float f0 = __expf(wc1.z), f1 = __expf(wc1.w), f2 = __expf(wc2.x),
                    f3 = __expf(wc2.y), f4 = __expf(wc2.z), f5 = __expf(wc2.w);
        const float rb1 = 1.0f / (f0 + f1 + f2 + f3 + f4 + f5);
        const float q = sw1 * inv_x3_1;
        const float q4 = (q * q) * (q * q);
        const float gr1 = sw1 * (1.0f - __powf(1.0f + q4, -0.25f));
        const float pw1 = __powf(sat1, bfn1);
        const float ex1 = __expf(lam * sat1) - 1.0f;
        const float bsum1 = f0 * gr1 + f1 * (pow10_1 * sw1) + f2 * (bfmax1 * pw1) +
                            f3 * (bfmax1 * sat1) + f4 * (b1o4 * ex1) +
                            f5 * (b1o5 * fmaxf(sat1 - th1, 0.0f));
        const float bf1 = fminf(bsum1 * rb1, sw1);
        sw1 -= bf1;

        sat2 = clip01(sw2 * inv_msw2);
        const float c0 = __expf(wc3.x), c1 = __expf(wc3.y), c2 = __expf(wc3.z),
                    c3 = __expf(wc3.w), c4 = __expf(wc4.x), c5 = __expf(wc4.y);
        const float rb2 = 1.0f / (c0 + c1 + c2 + c3 + c4 + c5);
        const float u = sw2 * inv_x3_2;
        const float u4 = (u * u) * (u * u);
        const float gr2 = sw2 * (1.0f - __powf(1.0f + u4, -0.25f));
        const float pw2 = __powf(sat2, bfn2);
        const float t10 = pow10_2 * sw2;
        const float bsum2 = c0 * gr2 + c1 * t10 + c2 * (bfmax2 * pw2) +
                            c3 * (bfmax2 * sat2) + c4 * (bfmax2 * sat2 * sat2) +
                            c5 * (t10 * sat2);
        const float bf2 = fminf(bsum2 * rb2, sw2);
        sw2 -= bf2;

        const size_t o = (size_t)t * N_GRID + g;
        surf_o[o] = surf;
        base_o[o] = bf1 + bf2;
        gate_o[o] = (unsigned char)((g4 > 0.5f ? 1 : 0) | (g5 > 0.5f ? 2 : 0));

        xc0 = xn0; xc1 = xn1; xc2 = xn2;
        wc0 = wn0; wc1 = wn1; wc2 = wn2; wc3 = wn3; wc4 = wn4; wc5 = wn5;
    }
}

// ---------------------------------------------------------------------------
// Kernel 3: unit-hydrograph routing + gate blend.
// ---------------------------------------------------------------------------
__global__ __launch_bounds__(256)
void route_kernel(const float* __restrict__ surf,
                  const float* __restrict__ base,
                  const float* __restrict__ uh1,
                  const float* __restrict__ uh2,
                  const unsigned char* __restrict__ gates,
                  float* __restrict__ out)
{
    const int g = blockIdx.x * 256 + threadIdx.x;
    if (g >= N_GRID) return;
    const int t = blockIdx.y;
    const size_t o = (size_t)t * N_GRID + g;

    const unsigned char gb = gates[o];
    const float s0 = surf[o];
    const float b0 = base[o];

    float accs = 0.0f, accb = 0.0f;
    #pragma unroll
    for (int lag = 0; lag < UH_LEN; ++lag) {
        const int tt = t - lag;
        const float sv = (tt >= 0) ? surf[(size_t)tt * N_GRID + g] : 0.0f;
        const float bv = (tt >= 0) ? base[(size_t)tt * N_GRID + g] : 0.0f;
        accs += uh1[lag * N_GRID + g] * sv;
        accb += uh2[lag * N_GRID + g] * bv;
    }
    const float qs = (gb & 1) ? accs : s0;
    const float qb = (gb & 2) ? accb : b0;
    out[o] = qs + qb;
}

// ---------------------------------------------------------------------------
extern "C" void kernel_launch(void* const* d_in, const int* in_sizes, int n_in,
                              void* d_out, int out_size, void* d_ws, size_t ws_size,
                              hipStream_t stream)
{
    const float* x_phy = (const float*)d_in[0];   // (T, G, 3)
    const float* wts   = (const float*)d_in[1];   // (T, G, 24)
    const float* hyb   = (const float*)d_in[2];   // (G, 32)
    float* out = (float*)d_out;                   // (T, G)

    const size_t uh_bytes = (size_t)UH_LEN * N_GRID * 4;
    // Big path: 21 fp32 planes + gate byte plane + surf + base + 2 uh
    const size_t big_need = TG * (21 * 4 + 1 + 2 * 4) + 2 * uh_bytes;

    if (ws_size >= big_need) {
        float* planes = (float*)d_ws;                       // 21 * TG floats
        unsigned char* gbits = (unsigned char*)(planes + 21 * TG);  // TG bytes
        float* surf = (float*)(gbits + TG);
        float* base = surf + TG;
        float* uh1  = base + TG;
        float* uh2  = uh1 + (size_t)UH_LEN * N_GRID;

        prep_kernel<<<dim3((N_GRID + 255) / 256, T_STEPS), dim3(256), 0, stream>>>(
            x_phy, wts, hyb, planes, gbits);
        uh_kernel<<<dim3((N_GRID + 255) / 256), dim3(256), 0, stream>>>(hyb, uh1, uh2);
        scan_planes_kernel<<<dim3((N_GRID + 63) / 64), dim3(64), 0, stream>>>(
            planes, gbits, hyb, surf, base);
        route_kernel<<<dim3((N_GRID + 255) / 256, T_STEPS), dim3(256), 0, stream>>>(
            surf, base, uh1, uh2, gbits, out);
    } else {
        // Fallback (round-1 structure, ~26.5 MB)
        float* surf = (float*)d_ws;
        float* base = surf + TG;
        float* uh1  = base + TG;
        float* uh2  = uh1 + (size_t)UH_LEN * N_GRID;
        unsigned char* gbits = (unsigned char*)(uh2 + (size_t)UH_LEN * N_GRID);

        uh_kernel<<<dim3((N_GRID + 255) / 256), dim3(256), 0, stream>>>(hyb, uh1, uh2);
        scan_kernel<<<dim3((N_GRID + 63) / 64), dim3(64), 0, stream>>>(
            x_phy, wts, hyb, surf, base, gbits);
        route_kernel<<<dim3((N_GRID + 255) / 256, T_STEPS), dim3(256), 0, stream>>>(
            surf, base, uh1, uh2, gbits, out);
    }
}

// Round 3
// 3818.275 us; speedup vs baseline: 1.3241x; 1.3241x over previous
//
#include <hip/hip_runtime.h>
#include <cstdint>
#include <cmath>

#define T_STEPS 1460
#define N_GRID  2000
#define UH_LEN  15
#define NZ      1e-6f
#define NB      32                   // 64-cell blocks (covers 2048 cells)
#define NPLANE  24                   // 23 used + 1 pad (16B-aligned record)
#define SLOT_FLOATS (NPLANE * 64)    // 1536 floats = 6144 B per (block, t)
#define DEPTH   8                    // LDS ring slots

static const size_t TG = (size_t)T_STEPS * N_GRID;

// sigmoid-bounded parameter transform (matches ref: lo + sigmoid(x)*(hi-lo))
__device__ __forceinline__ float pb(float x, float lo, float hi) {
    float s = 1.0f / (1.0f + expf(-x));
    return lo + s * (hi - lo);
}

__device__ __forceinline__ float clip01(float x) {
    return fminf(fmaxf(x, NZ), 1.0f);
}

// gate = round(sigmoid(x)) with round-half-to-even; (x>0) except near 0.
__device__ __forceinline__ float gatef(float x) {
    if (fabsf(x) < 1e-4f) {
        double s = 1.0 / (1.0 + exp(-(double)x));
        return (float)rint(s);
    }
    return (x > 0.0f) ? 1.0f : 0.0f;
}

// ---------------------------------------------------------------------------
// Kernel 1: per-cell unit hydrograph weights (softmax over 15 lags, 2 sets)
// ---------------------------------------------------------------------------
__global__ __launch_bounds__(256)
void uh_kernel(const float* __restrict__ hyb,
               float* __restrict__ uh1, float* __restrict__ uh2)
{
    const int g = blockIdx.x * 256 + threadIdx.x;
    if (g >= N_GRID) return;
    const float* h = hyb + (size_t)g * 32;
    const float a1 = pb(h[28], 0.3f, 20.0f);
    const float b1 = pb(h[29], 0.01f, 5.0f);
    const float a2 = pb(h[30], 0.5f, 13.0f);
    const float b2 = pb(h[31], 0.15f, 1.5f);

    float lw[UH_LEN];
    {
        float m = -1e30f;
        #pragma unroll
        for (int k = 0; k < UH_LEN; ++k) {
            const float kk = (float)(k + 1);
            lw[k] = (a1 - 1.0f) * logf(kk) - kk / b1;
            m = fmaxf(m, lw[k]);
        }
        float s = 0.0f;
        #pragma unroll
        for (int k = 0; k < UH_LEN; ++k) { lw[k] = expf(lw[k] - m); s += lw[k]; }
        const float inv = 1.0f / s;
        #pragma unroll
        for (int k = 0; k < UH_LEN; ++k) uh1[k * N_GRID + g] = lw[k] * inv;
    }
    {
        float m = -1e30f;
        #pragma unroll
        for (int k = 0; k < UH_LEN; ++k) {
            const float kk = (float)(k + 1);
            lw[k] = (a2 - 1.0f) * logf(kk) - kk / b2;
            m = fmaxf(m, lw[k]);
        }
        float s = 0.0f;
        #pragma unroll
        for (int k = 0; k < UH_LEN; ++k) { lw[k] = expf(lw[k] - m); s += lw[k]; }
        const float inv = 1.0f / s;
        #pragma unroll
        for (int k = 0; k < UH_LEN; ++k) uh2[k * N_GRID + g] = lw[k] * inv;
    }
}

// ---------------------------------------------------------------------------
// Kernel P: parallel pre-pass -> blocked stream.
// stream[((b*T + t) * NPLANE + p) * 64 + c], b = cell block, c = cell % 64.
//   p0 temp, p1 pet, p2 pshed, p3..8 wi (softmax-normalized),
//   p9..14 wb1, p15..20 wb2, p21 g0, p22 g1, p23 pad.
// gate byte plane (t,g): bit0=g4 bit1=g5 (for routing).
// ---------------------------------------------------------------------------
__global__ __launch_bounds__(256)
void prep_kernel(const float* __restrict__ xphy,
                 const float* __restrict__ wts,
                 const float* __restrict__ hyb,
                 float* __restrict__ stream,
                 unsigned char* __restrict__ gate_o)
{
    const int gid = blockIdx.x * 256 + threadIdx.x;  // 0..2047
    if (gid >= NB * 64) return;
    const int t = blockIdx.y;
    const int b = gid >> 6, c = gid & 63;
    float* sp = stream + ((size_t)b * T_STEPS + t) * SLOT_FLOATS;

    if (gid >= N_GRID) {    // pad cells: write zeros (defined, harmless)
        #pragma unroll
        for (int p = 0; p < NPLANE; ++p) sp[p * 64 + c] = 0.0f;
        return;
    }

    const size_t idx = (size_t)t * N_GRID + gid;
    const float* xp = xphy + idx * 3;
    const float prcp = xp[0], temp = xp[1], pet = xp[2];

    float w[24];
    const float4* wp = (const float4*)(wts + idx * 24);
    #pragma unroll
    for (int k = 0; k < 6; ++k) {
        float4 v = wp[k];
        w[4*k] = v.x; w[4*k+1] = v.y; w[4*k+2] = v.z; w[4*k+3] = v.w;
    }

    float e[18];
    #pragma unroll
    for (int k = 0; k < 18; ++k) e[k] = __expf(w[k]);
    float s0 = 0.f, s1 = 0.f, s2 = 0.f;
    #pragma unroll
    for (int k = 0; k < 6; ++k) { s0 += e[k]; s1 += e[6+k]; s2 += e[12+k]; }
    const float r0 = 1.0f / s0, r1 = 1.0f / s1, r2 = 1.0f / s2;

    const float g0 = gatef(w[18]);
    const float g1 = gatef(w[19]);
    const float g2 = gatef(w[20]);
    const float g3 = gatef(w[21]);
    const float g4 = gatef(w[22]);
    const float g5 = gatef(w[23]);

    const float* h = hyb + (size_t)gid * 32;
    const float fc = pb(h[24], 0.0f, 1.0f);
    const float fs = pb(h[25], 0.0f, 1.0f);
    const float canopy = pet * (fc * (1.0f - fs));
    const float pshed = (temp >= 0.0f) ? fmaxf(prcp - canopy * g2, 0.0f)
                                       : fmaxf(prcp - canopy * g3, 0.0f);

    sp[0 * 64 + c] = temp;
    sp[1 * 64 + c] = pet;
    sp[2 * 64 + c] = pshed;
    #pragma unroll
    for (int k = 0; k < 6; ++k) {
        sp[(3 + k)  * 64 + c] = e[k]      * r0;
        sp[(9 + k)  * 64 + c] = e[6 + k]  * r1;
        sp[(15 + k) * 64 + c] = e[12 + k] * r2;
    }
    sp[21 * 64 + c] = g0;
    sp[22 * 64 + c] = g1;
    sp[23 * 64 + c] = 0.0f;
    gate_o[idx] = (unsigned char)((g4 > 0.5f ? 1 : 0) | (g5 > 0.5f ? 2 : 0));
}

// ---------------------------------------------------------------------------
// Async global->LDS: one slot = 6 width-16 DMA loads (6144 B).
// LDS dest = wave-uniform base + lane*16 (lane0's pointer is the base).
// ---------------------------------------------------------------------------
__device__ __forceinline__ void load_slot(const float* sp, float* lp, int lane)
{
    #pragma unroll
    for (int i = 0; i < 6; ++i) {
        __builtin_amdgcn_global_load_lds(
            (const __attribute__((address_space(1))) void*)(sp + i * 256 + lane * 4),
            (__attribute__((address_space(3))) void*)(lp + i * 256 + lane * 4),
            16, 0, 0);
    }
}

// ---------------------------------------------------------------------------
// Kernel S: sequential scan with a structurally-enforced LDS ring pipeline.
// One wave per 64 cells; DEPTH=8 slots; explicit vmcnt fencing.
// ---------------------------------------------------------------------------
__global__ __launch_bounds__(64, 1)
void scan_stream_kernel(const float* __restrict__ stream,
                        const float* __restrict__ hyb,
                        float* __restrict__ surf_o,
                        float* __restrict__ base_o)
{
    __shared__ float lds[DEPTH * SLOT_FLOATS];   // 48 KB
    const int lane = threadIdx.x;
    const int b = blockIdx.x;
    const int g = b * 64 + lane;
    const int gc = (g < N_GRID) ? g : (N_GRID - 1);   // clamp params for pad lanes

    const float* h = hyb + (size_t)gc * 32;
    const float inf_pc   = pb(h[0],  0.0f,   1.0f);
    const float hbv_beta = pb(h[1],  0.5f,   3.0f);
    const float vic_bexp = pb(h[2],  0.001f, 3.0f);
    const float hmets_al = pb(h[3],  0.3f,   1.0f);
    const float x3_1     = pb(h[4],  20.0f,  300.0f);
    const float bfc1     = pb(h[5],  -8.0f,  -2.0f);
    const float bfn1     = pb(h[6],  1.0f,   5.0f);
    const float bfmax1   = pb(h[7],  0.1f,   200.0f);
    const float lam      = pb(h[8],  0.1f,   0.5f);
    const float th1      = pb(h[9],  0.0001f,0.9999f);
    const float max_perc = pb(h[10], 1.0f,   50.0f);
    const float sfc      = pb(h[11], 0.0001f,0.9999f);
    const float crise    = pb(h[12], 0.1f,   50.0f);
    const float bfmax2   = pb(h[13], 0.1f,   100.0f);
    const float x3_2     = pb(h[14], 50.0f,  500.0f);
    const float bfc2     = pb(h[15], -8.0f,  -2.0f);
    const float bfn2     = pb(h[16], 1.0f,   5.0f);
    const float Tbf      = pb(h[17], -5.0f,  2.0f);
    const float Kf       = pb(h[18], 0.0f,   5.0f);
    const float ddf_min  = pb(h[19], 1.5f,   3.0f);
    const float ddf_plus = pb(h[20], 0.0f,   5.0f);
    const float Kcum     = pb(h[21], 0.01f,  0.2f);
    const float Tbm      = pb(h[22], -1.0f,  1.0f);
    const float swi      = pb(h[23], 0.0f,   0.4f);
    const float msw1     = pb(h[26], 50.0f,  500.0f);
    const float msw2     = pb(h[27], 50.0f,  500.0f);

    const float inv_msw1 = 1.0f / msw1;
    const float inv_msw2 = 1.0f / msw2;
    const float pow10_1  = powf(10.0f, bfc1);
    const float pow10_2  = powf(10.0f, bfc2);
    const float inv_x3_1 = 1.0f / x3_1;
    const float inv_x3_2 = 1.0f / x3_2;
    const float b1o4     = bfmax1 / expm1f(lam);
    const float b1o5     = bfmax1 / (1.0f - th1);
    const float perc_fac = max_perc / (1.0f - sfc);

    const float* src = stream + (size_t)b * T_STEPS * SLOT_FLOATS;

    // prologue: issue slots 0..DEPTH-2 (42 loads outstanding)
    for (int s = 0; s < DEPTH - 1; ++s)
        load_slot(src + (size_t)s * SLOT_FLOATS, lds + s * SLOT_FLOATS, lane);

    float snow = NZ, liq = NZ, cum = NZ, sw1 = NZ, sw2 = NZ;

    for (int t = 0; t < T_STEPS; ++t) {
        if (t + DEPTH - 1 < T_STEPS) {
            const int ts = t + DEPTH - 1;
            load_slot(src + (size_t)ts * SLOT_FLOATS,
                      lds + (ts & (DEPTH - 1)) * SLOT_FLOATS, lane);
            // >=42 vmem ops are newer than slot t's loads -> slot t landed.
            asm volatile("s_waitcnt vmcnt(42)" ::: "memory");
        } else {
            asm volatile("s_waitcnt vmcnt(0)" ::: "memory");
        }

        const float* L = lds + (t & (DEPTH - 1)) * SLOT_FLOATS;
        const float temp  = L[0 * 64 + lane];
        const float pet   = L[1 * 64 + lane];
        const float pshed = L[2 * 64 + lane];
        const float a0 = L[3 * 64 + lane],  a1 = L[4 * 64 + lane];
        const float a2 = L[5 * 64 + lane],  a3 = L[6 * 64 + lane];
        const float a4 = L[7 * 64 + lane],  a5 = L[8 * 64 + lane];
        const float f0 = L[9 * 64 + lane],  f1 = L[10 * 64 + lane];
        const float f2 = L[11 * 64 + lane], f3 = L[12 * 64 + lane];
        const float f4 = L[13 * 64 + lane], f5 = L[14 * 64 + lane];
        const float c0 = L[15 * 64 + lane], c1 = L[16 * 64 + lane];
        const float c2 = L[17 * 64 + lane], c3 = L[18 * 64 + lane];
        const float c4 = L[19 * 64 + lane], c5 = L[20 * 64 + lane];
        const float g0 = L[21 * 64 + lane], g1 = L[22 * 64 + lane];

        // === step math (identical to verified round-2 do_step) ===
        const float rain  = (temp >= 0.0f) ? pshed : 0.0f;
        const float snowf = (temp <  0.0f) ? pshed : 0.0f;

        const float refreeze = fminf(liq, Kf * fmaxf(Tbf - temp, 0.0f));
        snow = snow + snowf + refreeze;
        liq  = liq - refreeze;
        const float ddf = ddf_min + ddf_plus * (1.0f - __expf(-Kcum * cum));
        const float melt = fminf(snow, ddf * fmaxf(temp - Tbm, 0.0f));
        snow -= melt;
        cum = (snow < NZ) ? NZ : (cum + melt);
        liq += melt;
        const float overflow = fmaxf(liq - swi * snow, 0.0f);
        liq -= overflow;
        const float wavail = rain + overflow;

        float sat1 = clip01(sw1 * inv_msw1);
        const float dry1 = clip01(1.0f - sat1);
        const float p1 = __powf(sat1, hbv_beta);
        const float p2 = __powf(dry1, vic_bexp);
        const float infil = wavail *
            (a0 * inf_pc + a1 * (1.0f - p1) + a2 * p2 +
             a3 * (hmets_al * dry1) + a4 * (1.0f - sat1 * sat1) + a5);

        sw1 += infil;
        const float excess = fmaxf(sw1 - msw1, 0.0f);
        sw1 -= excess;
        const float surf = wavail - infil + excess;

        sat1 = clip01(sw1 * inv_msw1);
        const float perc = fminf(g0 * perc_fac * fmaxf(sat1 - sfc, 0.0f), sw1);
        sw1 -= perc; sw2 += perc;

        float sat2 = clip01(sw2 * inv_msw2);
        sat1 = clip01(sw1 * inv_msw1);
        const float capi = fminf(g1 * crise * (1.0f - sat1) * sat2, sw2);
        sw2 -= capi; sw1 += capi;

        sat1 = clip01(sw1 * inv_msw1);
        const float et = fminf(pet * sat1, sw1);
        sw1 -= et;

        sat1 = clip01(sw1 * inv_msw1);
        const float q = sw1 * inv_x3_1;
        const float q4 = (q * q) * (q * q);
        const float gr1 = sw1 * (1.0f - __powf(1.0f + q4, -0.25f));
        const float pw1 = __powf(sat1, bfn1);
        const float ex1 = __expf(lam * sat1) - 1.0f;
        const float bsum1 = f0 * gr1 + f1 * (pow10_1 * sw1) + f2 * (bfmax1 * pw1) +
                            f3 * (bfmax1 * sat1) + f4 * (b1o4 * ex1) +
                            f5 * (b1o5 * fmaxf(sat1 - th1, 0.0f));
        const float bf1 = fminf(bsum1, sw1);
        sw1 -= bf1;

        sat2 = clip01(sw2 * inv_msw2);
        const float u = sw2 * inv_x3_2;
        const float u4 = (u * u) * (u * u);
        const float gr2 = sw2 * (1.0f - __powf(1.0f + u4, -0.25f));
        const float pw2 = __powf(sat2, bfn2);
        const float t10 = pow10_2 * sw2;
        const float bsum2 = c0 * gr2 + c1 * t10 + c2 * (bfmax2 * pw2) +
                            c3 * (bfmax2 * sat2) + c4 * (bfmax2 * sat2 * sat2) +
                            c5 * (t10 * sat2);
        const float bf2 = fminf(bsum2, sw2);
        sw2 -= bf2;

        if (g < N_GRID) {
            const size_t o = (size_t)t * N_GRID + g;
            surf_o[o] = surf;
            base_o[o] = bf1 + bf2;
        }
    }
}

// ---------------------------------------------------------------------------
// Kernel S-B (fallback for small ws): round-1 scan on raw inputs.
// ---------------------------------------------------------------------------
__global__ __launch_bounds__(64)
void scan_kernel(const float* __restrict__ xphy,
                 const float* __restrict__ wts,
                 const float* __restrict__ hyb,
                 float* __restrict__ surf_o,
                 float* __restrict__ base_o,
                 unsigned char* __restrict__ gate_o)
{
    const int g = blockIdx.x * 64 + threadIdx.x;
    if (g >= N_GRID) return;

    const float* h = hyb + (size_t)g * 32;
    const float inf_pc   = pb(h[0],  0.0f,   1.0f);
    const float hbv_beta = pb(h[1],  0.5f,   3.0f);
    const float vic_bexp = pb(h[2],  0.001f, 3.0f);
    const float hmets_al = pb(h[3],  0.3f,   1.0f);
    const float x3_1     = pb(h[4],  20.0f,  300.0f);
    const float bfc1     = pb(h[5],  -8.0f,  -2.0f);
    const float bfn1     = pb(h[6],  1.0f,   5.0f);
    const float bfmax1   = pb(h[7],  0.1f,   200.0f);
    const float lam      = pb(h[8],  0.1f,   0.5f);
    const float th1      = pb(h[9],  0.0001f,0.9999f);
    const float max_perc = pb(h[10], 1.0f,   50.0f);
    const float sfc      = pb(h[11], 0.0001f,0.9999f);
    const float crise    = pb(h[12], 0.1f,   50.0f);
    const float bfmax2   = pb(h[13], 0.1f,   100.0f);
    const float x3_2     = pb(h[14], 50.0f,  500.0f);
    const float bfc2     = pb(h[15], -8.0f,  -2.0f);
    const float bfn2     = pb(h[16], 1.0f,   5.0f);
    const float Tbf      = pb(h[17], -5.0f,  2.0f);
    const float Kf       = pb(h[18], 0.0f,   5.0f);
    const float ddf_min  = pb(h[19], 1.5f,   3.0f);
    const float ddf_plus = pb(h[20], 0.0f,   5.0f);
    const float Kcum     = pb(h[21], 0.01f,  0.2f);
    const float Tbm      = pb(h[22], -1.0f,  1.0f);
    const float swi      = pb(h[23], 0.0f,   0.4f);
    const float fc       = pb(h[24], 0.0f,   1.0f);
    const float fs       = pb(h[25], 0.0f,   1.0f);
    const float msw1     = pb(h[26], 50.0f,  500.0f);
    const float msw2     = pb(h[27], 50.0f,  500.0f);

    const float inv_msw1  = 1.0f / msw1;
    const float inv_msw2  = 1.0f / msw2;
    const float canopy_fac = fc * (1.0f - fs);
    const float pow10_1   = powf(10.0f, bfc1);
    const float pow10_2   = powf(10.0f, bfc2);
    const float inv_x3_1  = 1.0f / x3_1;
    const float inv_x3_2  = 1.0f / x3_2;
    const float b1o4      = bfmax1 / expm1f(lam);
    const float b1o5      = bfmax1 / (1.0f - th1);
    const float perc_fac  = max_perc / (1.0f - sfc);

    float snow = NZ, liq = NZ, cum = NZ, sw1 = NZ, sw2 = NZ;

    for (int t = 0; t < T_STEPS; ++t) {
        const size_t idx = (size_t)t * N_GRID + g;
        const float* xp = xphy + idx * 3;
        const float prcp = xp[0], temp = xp[1], pet = xp[2];
        float4 wc0, wc1, wc2, wc3, wc4, wc5;
        const float4* wp = (const float4*)(wts + idx * 24);
        wc0 = wp[0]; wc1 = wp[1]; wc2 = wp[2]; wc3 = wp[3]; wc4 = wp[4]; wc5 = wp[5];

        const float g0 = gatef(wc4.z);
        const float g1 = gatef(wc4.w);
        const float g2 = gatef(wc5.x);
        const float g3 = gatef(wc5.y);
        const float g4 = gatef(wc5.z);
        const float g5 = gatef(wc5.w);

        float rain  = (temp >= 0.0f) ? prcp : 0.0f;
        float snowf = (temp <  0.0f) ? prcp : 0.0f;
        const float canopy = pet * canopy_fac;
        rain  = fmaxf(rain  - canopy * g2, 0.0f);
        snowf = fmaxf(snowf - canopy * g3, 0.0f);

        const float refreeze = fminf(liq, Kf * fmaxf(Tbf - temp, 0.0f));
        snow = snow + snowf + refreeze;
        liq  = liq - refreeze;
        const float ddf = ddf_min + ddf_plus * (1.0f - __expf(-Kcum * cum));
        const float melt = fminf(snow, ddf * fmaxf(temp - Tbm, 0.0f));
        snow -= melt;
        cum = (snow < NZ) ? NZ : (cum + melt);
        liq += melt;
        const float overflow = fmaxf(liq - swi * snow, 0.0f);
        liq -= overflow;
        const float wavail = rain + overflow;

        float sat1 = clip01(sw1 * inv_msw1);
        const float dry1 = clip01(1.0f - sat1);
        const float e0 = __expf(wc0.x), e1 = __expf(wc0.y), e2 = __expf(wc0.z),
                    e3 = __expf(wc0.w), e4 = __expf(wc1.x), e5 = __expf(wc1.y);
        const float rsi = 1.0f / (e0 + e1 + e2 + e3 + e4 + e5);
        const float p1 = __powf(sat1, hbv_beta);
        const float p2 = __powf(dry1, vic_bexp);
        const float infil = wavail * rsi *
            (e0 * inf_pc + e1 * (1.0f - p1) + e2 * p2 +
             e3 * (hmets_al * dry1) + e4 * (1.0f - sat1 * sat1) + e5);

        sw1 += infil;
        const float excess = fmaxf(sw1 - msw1, 0.0f);
        sw1 -= excess;
        const float surf = wavail - infil + excess;

        sat1 = clip01(sw1 * inv_msw1);
        const float perc = fminf(g0 * perc_fac * fmaxf(sat1 - sfc, 0.0f), sw1);
        sw1 -= perc; sw2 += perc;

        float sat2 = clip01(sw2 * inv_msw2);
        sat1 = clip01(sw1 * inv_msw1);
        const float capi = fminf(g1 * crise * (1.0f - sat1) * sat2, sw2);
        sw2 -= capi; sw1 += capi;

        sat1 = clip01(sw1 * inv_msw1);
        const float et = fminf(pet * sat1, sw1);
        sw1 -= et;

        sat1 = clip01(sw1 * inv_msw1);
        const float f0 = __expf(wc1.z), f1 = __expf(wc1.w), f2 = __expf(wc2.x),
                    f3 = __expf(wc2.y), f4 = __expf(wc2.z), f5 = __expf(wc2.w);
        const float rb1 = 1.0f / (f0 + f1 + f2 + f3 + f4 + f5);
        const float q = sw1 * inv_x3_1;
        const float q4 = (q * q) * (q * q);
        const float gr1 = sw1 * (1.0f - __powf(1.0f + q4, -0.25f));
        const float pw1 = __powf(sat1, bfn1);
        const float ex1 = __expf(lam * sat1) - 1.0f;
        const float bsum1 = f0 * gr1 + f1 * (pow10_1 * sw1) + f2 * (bfmax1 * pw1) +
                            f3 * (bfmax1 * sat1) + f4 * (b1o4 * ex1) +
                            f5 * (b1o5 * fmaxf(sat1 - th1, 0.0f));
        const float bf1 = fminf(bsum1 * rb1, sw1);
        sw1 -= bf1;

        sat2 = clip01(sw2 * inv_msw2);
        const float c0 = __expf(wc3.x), c1 = __expf(wc3.y), c2 = __expf(wc3.z),
                    c3 = __expf(wc3.w), c4 = __expf(wc4.x), c5 = __expf(wc4.y);
        const float rb2 = 1.0f / (c0 + c1 + c2 + c3 + c4 + c5);
        const float u = sw2 * inv_x3_2;
        const float u4 = (u * u) * (u * u);
        const float gr2 = sw2 * (1.0f - __powf(1.0f + u4, -0.25f));
        const float pw2 = __powf(sat2, bfn2);
        const float t10 = pow10_2 * sw2;
        const float bsum2 = c0 * gr2 + c1 * t10 + c2 * (bfmax2 * pw2) +
                            c3 * (bfmax2 * sat2) + c4 * (bfmax2 * sat2 * sat2) +
                            c5 * (t10 * sat2);
        const float bf2 = fminf(bsum2 * rb2, sw2);
        sw2 -= bf2;

        surf_o[idx] = surf;
        base_o[idx] = bf1 + bf2;
        gate_o[idx] = (unsigned char)((g4 > 0.5f ? 1 : 0) | (g5 > 0.5f ? 2 : 0));
    }
}

// ---------------------------------------------------------------------------
// Kernel 3: unit-hydrograph routing + gate blend.
// ---------------------------------------------------------------------------
__global__ __launch_bounds__(256)
void route_kernel(const float* __restrict__ surf,
                  const float* __restrict__ base,
                  const float* __restrict__ uh1,
                  const float* __restrict__ uh2,
                  const unsigned char* __restrict__ gates,
                  float* __restrict__ out)
{
    const int g = blockIdx.x * 256 + threadIdx.x;
    if (g >= N_GRID) return;
    const int t = blockIdx.y;
    const size_t o = (size_t)t * N_GRID + g;

    const unsigned char gb = gates[o];
    const float s0 = surf[o];
    const float b0 = base[o];

    float accs = 0.0f, accb = 0.0f;
    #pragma unroll
    for (int lag = 0; lag < UH_LEN; ++lag) {
        const int tt = t - lag;
        const float sv = (tt >= 0) ? surf[(size_t)tt * N_GRID + g] : 0.0f;
        const float bv = (tt >= 0) ? base[(size_t)tt * N_GRID + g] : 0.0f;
        accs += uh1[lag * N_GRID + g] * sv;
        accb += uh2[lag * N_GRID + g] * bv;
    }
    const float qs = (gb & 1) ? accs : s0;
    const float qb = (gb & 2) ? accb : b0;
    out[o] = qs + qb;
}

// ---------------------------------------------------------------------------
extern "C" void kernel_launch(void* const* d_in, const int* in_sizes, int n_in,
                              void* d_out, int out_size, void* d_ws, size_t ws_size,
                              hipStream_t stream)
{
    const float* x_phy = (const float*)d_in[0];   // (T, G, 3)
    const float* wts   = (const float*)d_in[1];   // (T, G, 24)
    const float* hyb   = (const float*)d_in[2];   // (G, 32)
    float* out = (float*)d_out;                   // (T, G)

    const size_t stream_f = (size_t)NB * T_STEPS * SLOT_FLOATS;   // 71,761,920
    const size_t uh_f     = (size_t)UH_LEN * N_GRID;
    const size_t big_need = stream_f * 4 + TG * (2 * 4 + 1) + 2 * uh_f * 4; // ~313.6 MB

    if (ws_size >= big_need) {
        float* strm = (float*)d_ws;
        float* surf = strm + stream_f;
        float* base = surf + TG;
        float* uh1  = base + TG;
        float* uh2  = uh1 + uh_f;
        unsigned char* gbits = (unsigned char*)(uh2 + uh_f);

        prep_kernel<<<dim3((NB * 64) / 256, T_STEPS), dim3(256), 0, stream>>>(
            x_phy, wts, hyb, strm, gbits);
        uh_kernel<<<dim3((N_GRID + 255) / 256), dim3(256), 0, stream>>>(hyb, uh1, uh2);
        scan_stream_kernel<<<dim3(NB), dim3(64), 0, stream>>>(strm, hyb, surf, base);
        route_kernel<<<dim3((N_GRID + 255) / 256, T_STEPS), dim3(256), 0, stream>>>(
            surf, base, uh1, uh2, gbits, out);
    } else {
        float* surf = (float*)d_ws;
        float* base = surf + TG;
        float* uh1  = base + TG;
        float* uh2  = uh1 + uh_f;
        unsigned char* gbits = (unsigned char*)(uh2 + uh_f);

        uh_kernel<<<dim3((N_GRID + 255) / 256), dim3(256), 0, stream>>>(hyb, uh1, uh2);
        scan_kernel<<<dim3((N_GRID + 63) / 64), dim3(64), 0, stream>>>(
            x_phy, wts, hyb, surf, base, gbits);
        route_kernel<<<dim3((N_GRID + 255) / 256, T_STEPS), dim3(256), 0, stream>>>(
            surf, base, uh1, uh2, gbits, out);
    }
}